// Round 4
// baseline (161.382 us; speedup 1.0000x reference)
//
#include <hip/hip_runtime.h>

// ECE: ece = sum_b | sum_{i in b} (conf_i - acc_i) | / n
// Bin: tt = ceil(c*15), bin b matches tt == b+1 (b in 0..14). Validity free:
// c<=0 -> tt<=0, c>1 -> tt>15, NaN -> 0 -- none match any bin.
//
// R1: LDS atomics serialize (~210 cyc/wave-inst). R2: LDS RMW chains (VALU 9.5%,
// 47us). R3: select-chain w/ launch_bounds(256,8) -> VGPR crushed to 32 ->
// compiler serialized loads -> ~3 KB in flight/CU -> same 47us.
// Invariant across R0/R2/R3: dur==48us regardless of VALU load => latency-bound
// on in-flight bytes, not any pipe.
// R4: 8x float4-pair unroll = 16 independent global_load_dwordx4 (16 KB/wave)
// issued before any compute; __launch_bounds__(256,4) gives the register
// budget (~100 VGPR) to hold them. 4 waves/SIMD x 16 KB ~= 64 KB in
// flight/CU -> latency ceiling ~170 GB/s/CU >> the ~25 GB/s/CU needed for
// the 5-6 TB/s memory roofline.

#define NB 15

__device__ __forceinline__ void proc4(float4 c, float4 a, float* __restrict__ bins) {
    float cv[4] = {c.x, c.y, c.z, c.w};
    float av[4] = {a.x, a.y, a.z, a.w};
#pragma unroll
    for (int j = 0; j < 4; ++j) {
        float v = cv[j];
        float d = v - av[j];
        int tt = (int)ceilf(v * 15.0f);   // valid => tt in 1..15
#pragma unroll
        for (int b = 0; b < NB; ++b)
            bins[b] += (tt == b + 1) ? d : 0.0f;   // b+1 is an inline const
    }
}

__global__ __launch_bounds__(256, 4) void ece_hist(
        const float* __restrict__ conf,
        const float* __restrict__ acc,
        float* __restrict__ partials,   // layout [NB][nblocks]
        int n4, int n, int nblocks) {
    float bins[NB];
#pragma unroll
    for (int b = 0; b < NB; ++b) bins[b] = 0.0f;

    const float4* __restrict__ c4 = (const float4*)conf;
    const float4* __restrict__ a4 = (const float4*)acc;
    const int stride = gridDim.x * blockDim.x;
    int i = blockIdx.x * blockDim.x + threadIdx.x;

    // 8-wide: 16 independent dwordx4 loads (16 KB/wave) in flight before
    // any compute. Interleaved c/a so waitcnt counts down pairwise.
    for (; i + 7 * stride < n4; i += 8 * stride) {
        float4 c0 = c4[i];
        float4 a0 = a4[i];
        float4 c1 = c4[i + stride];
        float4 a1 = a4[i + stride];
        float4 c2 = c4[i + 2 * stride];
        float4 a2 = a4[i + 2 * stride];
        float4 c3 = c4[i + 3 * stride];
        float4 a3 = a4[i + 3 * stride];
        float4 c4v = c4[i + 4 * stride];
        float4 a4v = a4[i + 4 * stride];
        float4 c5 = c4[i + 5 * stride];
        float4 a5 = a4[i + 5 * stride];
        float4 c6 = c4[i + 6 * stride];
        float4 a6 = a4[i + 6 * stride];
        float4 c7 = c4[i + 7 * stride];
        float4 a7 = a4[i + 7 * stride];
        proc4(c0, a0, bins);
        proc4(c1, a1, bins);
        proc4(c2, a2, bins);
        proc4(c3, a3, bins);
        proc4(c4v, a4v, bins);
        proc4(c5, a5, bins);
        proc4(c6, a6, bins);
        proc4(c7, a7, bins);
    }
    for (; i < n4; i += stride) proc4(c4[i], a4[i], bins);

    // scalar tail (n not divisible by 4) — block 0 only
    if (blockIdx.x == 0) {
        for (int k = n4 * 4 + (int)threadIdx.x; k < n; k += blockDim.x) {
            float v = conf[k];
            float d = v - acc[k];
            int tt = (int)ceilf(v * 15.0f);
#pragma unroll
            for (int b = 0; b < NB; ++b)
                bins[b] += (tt == b + 1) ? d : 0.0f;
        }
    }

    // wave reduction (64 lanes)
#pragma unroll
    for (int b = 0; b < NB; ++b) {
        float v = bins[b];
#pragma unroll
        for (int off = 32; off > 0; off >>= 1)
            v += __shfl_down(v, off, 64);
        bins[b] = v;
    }

    __shared__ float wsum[4][NB];       // 256 threads = 4 waves
    const int wave = threadIdx.x >> 6;
    const int lane = threadIdx.x & 63;
    if (lane == 0) {
#pragma unroll
        for (int b = 0; b < NB; ++b) wsum[wave][b] = bins[b];
    }
    __syncthreads();

    if (threadIdx.x < NB) {
        float s = wsum[0][threadIdx.x] + wsum[1][threadIdx.x]
                + wsum[2][threadIdx.x] + wsum[3][threadIdx.x];
        partials[threadIdx.x * nblocks + blockIdx.x] = s;   // no atomics
    }
}

__global__ __launch_bounds__(960) void ece_final(
        const float* __restrict__ partials,  // [NB][nblocks]
        float* __restrict__ out, int nblocks, float inv_n) {
    __shared__ float bsum[NB];
    const int wave = threadIdx.x >> 6;   // 15 waves, one per bin
    const int lane = threadIdx.x & 63;

    float s = 0.0f;
    for (int i = lane; i < nblocks; i += 64)
        s += partials[wave * nblocks + i];   // coalesced per wave
#pragma unroll
    for (int off = 32; off > 0; off >>= 1)
        s += __shfl_down(s, off, 64);
    if (lane == 0) bsum[wave] = s;
    __syncthreads();

    if (threadIdx.x == 0) {
        float t = 0.0f;
#pragma unroll
        for (int b = 0; b < NB; ++b) t += fabsf(bsum[b]);
        out[0] = t * inv_n;
    }
}

extern "C" void kernel_launch(void* const* d_in, const int* in_sizes, int n_in,
                              void* d_out, int out_size, void* d_ws, size_t ws_size,
                              hipStream_t stream) {
    const float* conf = (const float*)d_in[0];
    const float* acc  = (const float*)d_in[1];
    float* partials   = (float*)d_ws;
    float* out        = (float*)d_out;

    const int n  = in_sizes[0];
    const int n4 = n / 4;

    int nblocks = 2048;                          // 8 blocks/CU
    while ((size_t)NB * nblocks * sizeof(float) > ws_size && nblocks > 1)
        nblocks >>= 1;
    int max_grid = (n4 + 255) / 256;
    if (nblocks > max_grid) nblocks = max_grid;
    if (nblocks < 1) nblocks = 1;

    ece_hist<<<nblocks, 256, 0, stream>>>(conf, acc, partials, n4, n, nblocks);
    ece_final<<<1, 960, 0, stream>>>(partials, out, nblocks, 1.0f / (float)n);
}